// Round 16
// baseline (525.405 us; speedup 1.0000x reference)
//
#include <hip/hip_runtime.h>
#include <math.h>

// Problem constants
#define BB 4
#define TT 32
#define NF 8
#define FPF 8
#define SDIM 8
#define UU 64
#define SS 72
#define UNFOLDS 6

typedef short short8 __attribute__((ext_vector_type(8)));
typedef float f32x4 __attribute__((ext_vector_type(4)));
union Frag { uint4 u; short8 s; };

__device__ __forceinline__ float fast_sigmoid(float x) {
    float e = exp2f(-1.44269504f * x);
    return __builtin_amdgcn_rcpf(1.0f + e);
}

__device__ __forceinline__ ushort f2b(float f) {
    union { float f; uint u; } a;
    a.f = f;
    uint u = a.u;
    return (ushort)((u + 0x7FFFu + ((u >> 16) & 1u)) >> 16);
}

__device__ __forceinline__ float bcast_lane(float v, int lane) {
    return __uint_as_float(__builtin_amdgcn_readlane(__float_as_uint(v), lane));
}

// ============ prep sub-bodies ============
__device__ __forceinline__ void cvt_body(const float* __restrict__ in,
                                         ushort* __restrict__ outp, int idx) {
    int x = idx % 320;
    int r = idx / 320;
    int y = r % 160;
    int n = r / 160;
    const float* base = in + ((size_t)n * 3 * 160 + y) * 320 + x;
    float c0 = base[0];
    float c1 = base[160 * 320];
    float c2 = base[2 * 160 * 320];
    uint2 pk;
    pk.x = (uint)f2b(c0) | ((uint)f2b(c1) << 16);
    pk.y = (uint)f2b(c2);
    *(uint2*)(outp + ((size_t)((n * 164 + y + 2) * 328) + (x + 2)) * 4) = pk;
}

template <int HP, int WP, int H, int W, int CH>
__device__ __forceinline__ void halo_body(ushort* __restrict__ buf, int bid) {
    constexpr int TOPBOT = 2 * WP;
    constexpr int SIDE = WP - W;
    constexpr int NH = 2 * TOPBOT + H * SIDE;
    int idx = bid * 256 + threadIdx.x;
    if (idx >= 128 * NH) return;
    int n = idx / NH;
    int h = idx - n * NH;
    int y, x;
    if (h < TOPBOT) {
        y = h / WP;
        x = h % WP;
    } else if (h < 2 * TOPBOT) {
        int hh = h - TOPBOT;
        y = H + 2 + hh / WP;
        x = hh % WP;
    } else {
        int hh = h - 2 * TOPBOT;
        y = 2 + hh / SIDE;
        int xi = hh % SIDE;
        x = (xi < 2) ? xi : (W + xi);
    }
    ushort* p = buf + (((size_t)n * HP + y) * WP + x) * CH;
    if constexpr (CH == 4) {
        *(uint2*)p = make_uint2(0u, 0u);
    } else {
        uint4 z = make_uint4(0u, 0u, 0u, 0u);
#pragma unroll
        for (int i = 0; i < CH / 8; i++) *(uint4*)(p + i * 8) = z;
    }
}

__device__ __forceinline__ uint4 pack8(const ushort v[8]) {
    uint4 u;
    u.x = (uint)v[0] | ((uint)v[1] << 16);
    u.y = (uint)v[2] | ((uint)v[3] << 16);
    u.z = (uint)v[4] | ((uint)v[5] << 16);
    u.w = (uint)v[6] | ((uint)v[7] << 16);
    return u;
}

__device__ __forceinline__ void wswz1_body(const float* __restrict__ w, uint4* __restrict__ o,
                                           int i) {  // [0, 320)
    int lane = i & 63, s = i >> 6;
    int oc = lane & 15, q = lane >> 4;
    ushort v[8];
#pragma unroll
    for (int j = 0; j < 8; j++) {
        int k = q * 8 + j;
        int kx = k >> 2, c = k & 3;
        float f = (kx < 5 && c < 3) ? w[((oc * 3 + c) * 5 + s) * 5 + kx] : 0.f;
        v[j] = f2b(f);
    }
    o[i] = pack8(v);
}
__device__ __forceinline__ void wswz2_body(const float* __restrict__ w, uint4* __restrict__ o,
                                           int i) {  // [0, 1920)
    int lane = i & 63;
    int ct = (i >> 6) & 1;
    int s = i >> 7;
    int ky = s / 3, kxp = s % 3;
    int oc = ct * 16 + (lane & 15);
    int q = lane >> 4, h = q >> 1;
    int kx = 2 * kxp + h;
    ushort v[8];
#pragma unroll
    for (int j = 0; j < 8; j++) {
        int ch = (q & 1) * 8 + j;
        float f = (kx < 5) ? w[((oc * 16 + ch) * 5 + ky) * 5 + kx] : 0.f;
        v[j] = f2b(f);
    }
    o[i] = pack8(v);
}
__device__ __forceinline__ void wswz3_body(const float* __restrict__ w, uint4* __restrict__ o,
                                           int i) {  // [0, 1600)
    int lane = i & 63, s = i >> 6;
    int ky = s / 5, kx = s % 5;
    int oc = lane & 15, q = lane >> 4;
    ushort v[8];
#pragma unroll
    for (int j = 0; j < 8; j++) {
        int ch = q * 8 + j;
        float f = (oc < 8) ? w[((oc * 32 + ch) * 5 + ky) * 5 + kx] : 0.f;
        v[j] = f2b(f);
    }
    o[i] = pack8(v);
}

// ============ prep: cvt + halos + weight swizzles, ONE dispatch ============
__global__ __launch_bounds__(256) void prep_kernel(
    const float* __restrict__ in_seq, ushort* __restrict__ inp1, ushort* __restrict__ c1out,
    ushort* __restrict__ c2out, const float* __restrict__ c1w, const float* __restrict__ c2w,
    const float* __restrict__ c3w, uint4* __restrict__ wz1, uint4* __restrict__ wz2,
    uint4* __restrict__ wz3) {
    int bid = blockIdx.x;
    if (bid < 25600) {
        cvt_body(in_seq, inp1, bid * 256 + threadIdx.x);
    } else if (bid < 25600 + 2032) {
        int hb = bid - 25600;
        if (hb < 1296)
            halo_body<164, 328, 160, 320, 4>(inp1, hb);
        else if (hb < 1296 + 488)
            halo_body<84, 164, 80, 160, 16>(c1out, hb - 1296);
        else
            halo_body<44, 84, 40, 80, 32>(c2out, hb - 1784);
    } else {
        int i = (bid - 27632) * 256 + threadIdx.x;  // [0, 3840)
        if (i < 320)
            wswz1_body(c1w, wz1, i);
        else if (i < 2240)
            wswz2_body(c2w, wz2, i - 320);
        else
            wswz3_body(c3w, wz3, i - 2240);
    }
}

// ============ conv1: [128][164][328][4] -> [128][84][164][16], 5 ksteps (ky) ============
__global__ __launch_bounds__(256) void conv1_mfma(const ushort* __restrict__ inp,
                                                  const uint4* __restrict__ wswz,
                                                  const float* __restrict__ bias,
                                                  ushort* __restrict__ outp) {
    const int lane = threadIdx.x & 63;
    const int wid = threadIdx.x >> 6;
    const int col = lane & 15, q = lane >> 4;

    Frag A[5];
#pragma unroll
    for (int s = 0; s < 5; s++) A[s].u = wswz[s * 64 + lane];
    float b0 = bias[q * 4 + 0], b1 = bias[q * 4 + 1], b2 = bias[q * 4 + 2], b3 = bias[q * 4 + 3];

    int gw = blockIdx.x * 4 + wid;
#pragma unroll
    for (int t = 0; t < 4; t++) {
        int p0 = gw * 64 + t * 16;
        int n = p0 / 12800;
        int rem = p0 - n * 12800;
        int oy = rem / 160;
        int ox0 = rem - oy * 160;
        int ox = ox0 + col;
        uint e0 = ((uint)(n * 164 + oy * 2) * 328u + (uint)(ox * 2 + 2 * q)) * 4u;
        f32x4 acc = {0.f, 0.f, 0.f, 0.f};
#pragma unroll
        for (int s = 0; s < 5; s++) {
            Frag B;
            B.u = *(const uint4*)(inp + e0 + (uint)s * (328u * 4u));
            acc = __builtin_amdgcn_mfma_f32_16x16x32_bf16(A[s].s, B.s, acc, 0, 0, 0);
        }
        uint oe = ((uint)(n * 84 + oy + 2) * 164u + (uint)(ox + 2)) * 16u + q * 4u;
        uint2 pk;
        pk.x = (uint)f2b(fmaxf(acc[0] + b0, 0.f)) | ((uint)f2b(fmaxf(acc[1] + b1, 0.f)) << 16);
        pk.y = (uint)f2b(fmaxf(acc[2] + b2, 0.f)) | ((uint)f2b(fmaxf(acc[3] + b3, 0.f)) << 16);
        *(uint2*)(outp + oe) = pk;
    }
}

// ============ conv2: [128][84][164][16] -> [128][44][84][32], 15 ksteps ============
__global__ __launch_bounds__(256) void conv2_mfma(const ushort* __restrict__ inp,
                                                  const uint4* __restrict__ wswz,
                                                  const float* __restrict__ bias,
                                                  ushort* __restrict__ outp) {
    const int lane = threadIdx.x & 63;
    const int wid = threadIdx.x >> 6;
    const int col = lane & 15, q = lane >> 4;
    const int h = q >> 1, chh = q & 1;

    int gw = blockIdx.x * 4 + wid;
    uint eb[4];
#pragma unroll
    for (int t = 0; t < 4; t++) {
        int p0 = gw * 64 + t * 16;
        int n = p0 / 3200;
        int rem = p0 - n * 3200;
        int oy = rem / 80;
        int ox0 = rem - oy * 80;
        eb[t] = ((uint)(n * 84 + oy * 2) * 164u + (uint)((ox0 + col) * 2 + h)) * 16u + chh * 8u;
    }
    f32x4 acc[4][2];
#pragma unroll
    for (int t = 0; t < 4; t++) {
        acc[t][0] = {0.f, 0.f, 0.f, 0.f};
        acc[t][1] = {0.f, 0.f, 0.f, 0.f};
    }
#pragma unroll
    for (int s = 0; s < 15; s++) {
        const int ky = s / 3, kxp = s % 3;
        Frag A0, A1;
        A0.u = wswz[(s * 2 + 0) * 64 + lane];
        A1.u = wswz[(s * 2 + 1) * 64 + lane];
        const uint d = (uint)ky * (164u * 16u) + (uint)kxp * 32u;
#pragma unroll
        for (int t = 0; t < 4; t++) {
            Frag B;
            B.u = *(const uint4*)(inp + eb[t] + d);
            acc[t][0] = __builtin_amdgcn_mfma_f32_16x16x32_bf16(A0.s, B.s, acc[t][0], 0, 0, 0);
            acc[t][1] = __builtin_amdgcn_mfma_f32_16x16x32_bf16(A1.s, B.s, acc[t][1], 0, 0, 0);
        }
    }
    float ba[2][4];
#pragma unroll
    for (int c = 0; c < 2; c++)
#pragma unroll
        for (int r = 0; r < 4; r++) ba[c][r] = bias[c * 16 + q * 4 + r];
#pragma unroll
    for (int t = 0; t < 4; t++) {
        int p0 = gw * 64 + t * 16;
        int n = p0 / 3200;
        int rem = p0 - n * 3200;
        int oy = rem / 80;
        int ox0 = rem - oy * 80;
        int ox = ox0 + col;
        uint oe = ((uint)(n * 44 + oy + 2) * 84u + (uint)(ox + 2)) * 32u;
#pragma unroll
        for (int c = 0; c < 2; c++) {
            uint2 pk;
            pk.x = (uint)f2b(fmaxf(acc[t][c][0] + ba[c][0], 0.f)) |
                   ((uint)f2b(fmaxf(acc[t][c][1] + ba[c][1], 0.f)) << 16);
            pk.y = (uint)f2b(fmaxf(acc[t][c][2] + ba[c][2], 0.f)) |
                   ((uint)f2b(fmaxf(acc[t][c][3] + ba[c][3], 0.f)) << 16);
            *(uint2*)(outp + oe + (uint)c * 16u + (uint)q * 4u) = pk;
        }
    }
}

// ============ conv3: [128][44][84][32] -> [128][800][8] f32 (NHWC), 25 ksteps ============
__global__ __launch_bounds__(256) void conv3_mfma(const ushort* __restrict__ inp,
                                                  const uint4* __restrict__ wswz,
                                                  const float* __restrict__ bias,
                                                  float* __restrict__ outp) {
    const int lane = threadIdx.x & 63;
    const int wid = threadIdx.x >> 6;
    const int col = lane & 15, q = lane >> 4;

    int gw = blockIdx.x * 4 + wid;
    uint eb[4];
#pragma unroll
    for (int t = 0; t < 4; t++) {
        int p0 = gw * 64 + t * 16;
        int n = p0 / 800;
        int pix = p0 - n * 800 + col;  // per-lane coords (row-wrap safe, OW=40)
        int oy = pix / 40;
        int ox = pix - oy * 40;
        eb[t] = ((uint)(n * 44 + oy * 2) * 84u + (uint)(ox * 2)) * 32u + q * 8u;
    }
    f32x4 acc[4];
#pragma unroll
    for (int t = 0; t < 4; t++) acc[t] = {0.f, 0.f, 0.f, 0.f};
#pragma unroll
    for (int s = 0; s < 25; s++) {
        const int ky = s / 5, kx = s % 5;
        Frag A;
        A.u = wswz[s * 64 + lane];
        const uint d = ((uint)ky * 84u + (uint)kx) * 32u;
#pragma unroll
        for (int t = 0; t < 4; t++) {
            Frag B;
            B.u = *(const uint4*)(inp + eb[t] + d);
            acc[t] = __builtin_amdgcn_mfma_f32_16x16x32_bf16(A.s, B.s, acc[t], 0, 0, 0);
        }
    }
    if (q < 2) {
        float b0 = bias[q * 4 + 0], b1 = bias[q * 4 + 1];
        float b2 = bias[q * 4 + 2], b3 = bias[q * 4 + 3];
#pragma unroll
        for (int t = 0; t < 4; t++) {
            int p0 = gw * 64 + t * 16;
            int n = p0 / 800;
            int p = p0 - n * 800 + col;
            float4 v;
            v.x = fmaxf(acc[t][0] + b0, 0.f);
            v.y = fmaxf(acc[t][1] + b1, 0.f);
            v.z = fmaxf(acc[t][2] + b2, 0.f);
            v.w = fmaxf(acc[t][3] + b3, 0.f);
            *(float4*)(outp + ((size_t)n * 800 + p) * 8 + q * 4) = v;
        }
    }
}

// ============ head: 256 threads, 4-way p-split + LDS reduce ============
__global__ __launch_bounds__(256) void head_kernel(const float* __restrict__ x,
                                                   const float* __restrict__ hw,
                                                   const float* __restrict__ hb,
                                                   float* __restrict__ feats) {
    __shared__ float part[4][64];
    int n = blockIdx.x;
    int tid = threadIdx.x;
    int lane = tid & 63;
    int c = tid >> 6;  // p-chunk 0..3
    int f = lane >> 3;
    int k = lane & 7;
    const float* xb = x + (size_t)n * 800 * 8 + f;
    const float* wb = hw + ((size_t)f * 800) * FPF + k;
    float acc = 0.0f;
    for (int p = c * 200; p < c * 200 + 200; p++)
        acc = fmaf(xb[(size_t)p * 8], wb[(size_t)p * FPF], acc);
    part[c][lane] = acc;
    __syncthreads();
    if (c == 0)
        feats[n * 64 + lane] = part[0][lane] + part[1][lane] + part[2][lane] + part[3][lane] +
                               hb[lane];
}

// ============ sensory256: block-local stats + semb + sensory, 128 blocks x 256 ============
__global__ __launch_bounds__(256) void sensory256(
    const float* __restrict__ feats, const float* __restrict__ speed,
    const float* __restrict__ sew1, const float* __restrict__ seb1,
    const float* __restrict__ sew2, const float* __restrict__ seb2,
    const float* __restrict__ inw, const float* __restrict__ inb,
    const float* __restrict__ ssig, const float* __restrict__ smu,
    const float* __restrict__ sw, const float* __restrict__ serev,
    float* __restrict__ wns, float* __restrict__ wds) {
    __shared__ float2 red[256];
    __shared__ float2 part[4][64];
    int bid = blockIdx.x;  // t*4 + b
    int t = bid >> 2;
    int b = bid & 3;
    int tid = threadIdx.x;
    int u = tid & 63;
    int c = tid >> 6;  // ss-chunk 0..3 (18 terms each)
    int n = b * TT + t;

    float s = 0.0f, q = 0.0f;
    for (int i = tid; i < 8192; i += 256) {
        float x = feats[i];
        s += x;
        q += x * x;
    }
    red[tid] = make_float2(s, q);
    __syncthreads();
    for (int off = 128; off > 0; off >>= 1) {
        if (tid < off) {
            float2 o = red[tid + off];
            float2 m = red[tid];
            red[tid] = make_float2(m.x + o.x, m.y + o.y);
        }
        __syncthreads();
    }
    float mean = red[0].x / 8192.0f;
    float var = fmaxf((red[0].y - 8192.0f * mean * mean) / 8191.0f, 0.0f);
    float inv = 1.0f / (sqrtf(var) + 1e-5f);

    float sp = speed[n];
    float hh[16];
#pragma unroll
    for (int j = 0; j < 16; j++) hh[j] = fmaxf(fmaf(sp, sew1[j], seb1[j]), 0.0f);
    float embv[SDIM];
#pragma unroll
    for (int k = 0; k < SDIM; k++) {
        float a = seb2[k];
#pragma unroll
        for (int j = 0; j < 16; j++) a = fmaf(hh[j], sew2[j * SDIM + k], a);
        embv[k] = tanhf(a);
    }

    float num = 0.0f, den = 0.0f;
    int ss0 = c * 18;
#pragma unroll
    for (int i = 0; i < 18; i++) {
        int ss = ss0 + i;
        float xsv = (ss < 64) ? feats[n * 64 + ss] * inv : embv[ss - 64];
        float inp = fmaf(xsv, inw[ss], inb[ss]);
        int idx = ss * UU + u;
        float x = (inp - smu[idx]) * ssig[idx];
        float act = sw[idx] * fast_sigmoid(x);
        num = fmaf(act, serev[idx], num);
        den += act;
    }
    part[c][u] = make_float2(num, den);
    __syncthreads();
    if (c == 0) {
        float2 p0 = part[0][u], p1 = part[1][u], p2 = part[2][u], p3 = part[3][u];
        wns[bid * UU + u] = p0.x + p1.x + p2.x + p3.x;
        wds[bid * UU + u] = p0.y + p1.y + p2.y + p3.y;
    }
}

// ============ LTC scan v5: SINGLE WAVE per batch — zero barriers, zero LDS ============
// Lane u owns post-neuron u and computes ALL 64 pre-synapses itself: num/den
// are complete per-lane (no cross-lane reduction). v broadcast via v_readlane
// with literal lane indices. Tests whether the 113us floor was sync (R6/R7
// both had barrier+LDS on the critical path) or compute.
__global__ __launch_bounds__(64, 1) void scan_kernel(
    const float* __restrict__ wns, const float* __restrict__ wds,
    const float* __restrict__ gleak, const float* __restrict__ vleak,
    const float* __restrict__ cm, const float* __restrict__ sigma,
    const float* __restrict__ mu, const float* __restrict__ wsyn,
    const float* __restrict__ erev, const float* __restrict__ outw,
    const float* __restrict__ outb, float* __restrict__ dout) {
    int b = blockIdx.x;
    int u = threadIdx.x;  // 0..63

    // all 64 pre rows for this lane's post u: 256 VGPRs pinned (<=512 budget)
    float sA[64], sB[64], wer[64], w_[64];
#pragma unroll
    for (int i = 0; i < 64; i++) {
        int idx = i * UU + u;
        float sg = sigma[idx];
        sA[i] = -1.44269504f * sg;
        sB[i] = -sA[i] * mu[idx];
        w_[i] = wsyn[idx];
        wer[i] = w_[i] * erev[idx];
    }
#pragma unroll
    for (int i = 0; i < 64; i++) {
        asm volatile("" : "+v"(sA[i]), "+v"(sB[i]), "+v"(wer[i]), "+v"(w_[i]));
    }
    float cmt = cm[u] * (float)UNFOLDS;
    float gl = gleak[u];
    float glvl = gl * vleak[u];
    float ow = outw[0], ob = outb[0];
    float v = 0.0f;

    float num_s = wns[(0 * BB + b) * UU + u];
    float den_s = wds[(0 * BB + b) * UU + u];
    for (int t = 0; t < TT; t++) {
        float nns = 0.f, nds = 0.f;
        if (t + 1 < TT) {
            nns = wns[((t + 1) * BB + b) * UU + u];
            nds = wds[((t + 1) * BB + b) * UU + u];
        }
#pragma unroll
        for (int k = 0; k < UNFOLDS; k++) {
            float num = num_s, den = den_s;
#pragma unroll
            for (int i = 0; i < 64; i++) {
                float vi = bcast_lane(v, i);  // v_readlane, literal lane
                float e = exp2f(fmaf(vi, sA[i], sB[i]));
                float r = __builtin_amdgcn_rcpf(1.0f + e);
                num = fmaf(wer[i], r, num);
                den = fmaf(w_[i], r, den);
            }
            float denom = cmt + gl + den + 1e-8f;
            v = (fmaf(cmt, v, glvl) + num) * __builtin_amdgcn_rcpf(denom);
        }
        dout[384 + (b * TT + t) * UU + u] = v;
        if (u == 0) dout[b * TT + t] = fmaf(v, ow, ob);
        if (t == TT - 1) dout[128 + b * UU + u] = v;
        num_s = nns;
        den_s = nds;
    }
}

extern "C" void kernel_launch(void* const* d_in, const int* in_sizes, int n_in,
                              void* d_out, int out_size, void* d_ws, size_t ws_size,
                              hipStream_t stream) {
    const float* in_seq = (const float*)d_in[0];
    const float* speed = (const float*)d_in[1];
    const float* c1w = (const float*)d_in[2];
    const float* c1b = (const float*)d_in[3];
    const float* c2w = (const float*)d_in[4];
    const float* c2b = (const float*)d_in[5];
    const float* c3w = (const float*)d_in[6];
    const float* c3b = (const float*)d_in[7];
    const float* hw = (const float*)d_in[8];
    const float* hb = (const float*)d_in[9];
    const float* sew1 = (const float*)d_in[10];
    const float* seb1 = (const float*)d_in[11];
    const float* sew2 = (const float*)d_in[12];
    const float* seb2 = (const float*)d_in[13];
    const float* inw = (const float*)d_in[14];
    const float* inb = (const float*)d_in[15];
    const float* gleak = (const float*)d_in[16];
    const float* vleak = (const float*)d_in[17];
    const float* cm = (const float*)d_in[18];
    const float* sigma = (const float*)d_in[19];
    const float* mu = (const float*)d_in[20];
    const float* wsyn = (const float*)d_in[21];
    const float* erev = (const float*)d_in[22];
    const float* ssig = (const float*)d_in[23];
    const float* smu = (const float*)d_in[24];
    const float* sw = (const float*)d_in[25];
    const float* serev = (const float*)d_in[26];
    const float* outw = (const float*)d_in[27];
    const float* outb = (const float*)d_in[28];

    char* ws = (char*)d_ws;
    float* out = (float*)d_out;

    size_t off = 0;
    auto alloc = [&](size_t bytes) {
        size_t o = off;
        off += (bytes + 255) & ~(size_t)255;
        return o;
    };
    ushort* inp1 = (ushort*)(ws + alloc((size_t)128 * 164 * 328 * 4 * 2));
    ushort* c1out = (ushort*)(ws + alloc((size_t)128 * 84 * 164 * 16 * 2));
    ushort* c2out = (ushort*)(ws + alloc((size_t)128 * 44 * 84 * 32 * 2));
    float* c3out = (float*)(ws + alloc((size_t)128 * 800 * 8 * 4));
    float* feats = (float*)(ws + alloc(8192 * 4));
    float* wns = (float*)(ws + alloc(8192 * 4));
    float* wds = (float*)(ws + alloc(8192 * 4));
    uint4* wz1 = (uint4*)(ws + alloc(5 * 64 * 16));
    uint4* wz2 = (uint4*)(ws + alloc(30 * 64 * 16));
    uint4* wz3 = (uint4*)(ws + alloc(25 * 64 * 16));

    // 1) prep: cvt + halo fills + weight swizzles
    prep_kernel<<<27647, 256, 0, stream>>>(in_seq, inp1, c1out, c2out, c1w, c2w, c3w, wz1,
                                           wz2, wz3);

    // 2-4) MFMA convs
    conv1_mfma<<<6400, 256, 0, stream>>>(inp1, wz1, c1b, c1out);
    conv2_mfma<<<1600, 256, 0, stream>>>(c1out, wz2, c2b, c2out);
    conv3_mfma<<<400, 256, 0, stream>>>(c2out, wz3, c3b, c3out);

    // 5) head
    head_kernel<<<128, 256, 0, stream>>>(c3out, hw, hb, feats);

    // 6) sensory (+block-local stats +semb)
    sensory256<<<128, 256, 0, stream>>>(feats, speed, sew1, seb1, sew2, seb2, inw, inb,
                                        ssig, smu, sw, serev, wns, wds);

    // 7) serial LTC scan: 1 wave per batch, no sync
    scan_kernel<<<BB, 64, 0, stream>>>(wns, wds, gleak, vleak, cm, sigma, mu, wsyn, erev,
                                       outw, outb, out);
}

// Round 17
// 253.104 us; speedup vs baseline: 2.0758x; 2.0758x over previous
//
#include <hip/hip_runtime.h>
#include <math.h>

// Problem constants
#define BB 4
#define TT 32
#define NF 8
#define FPF 8
#define SDIM 8
#define UU 64
#define SS 72
#define UNFOLDS 6

typedef short short8 __attribute__((ext_vector_type(8)));
typedef float f32x4 __attribute__((ext_vector_type(4)));
union Frag { uint4 u; short8 s; };

__device__ __forceinline__ float fast_sigmoid(float x) {
    float e = exp2f(-1.44269504f * x);
    return __builtin_amdgcn_rcpf(1.0f + e);
}

__device__ __forceinline__ ushort f2b(float f) {
    union { float f; uint u; } a;
    a.f = f;
    uint u = a.u;
    return (ushort)((u + 0x7FFFu + ((u >> 16) & 1u)) >> 16);
}

__device__ __forceinline__ float bcast_lane(float v, int lane) {
    return __uint_as_float(__builtin_amdgcn_readlane(__float_as_uint(v), lane));
}

// ============ prep sub-bodies ============
__device__ __forceinline__ void cvt_body(const float* __restrict__ in,
                                         ushort* __restrict__ outp, int idx) {
    int x = idx % 320;
    int r = idx / 320;
    int y = r % 160;
    int n = r / 160;
    const float* base = in + ((size_t)n * 3 * 160 + y) * 320 + x;
    float c0 = base[0];
    float c1 = base[160 * 320];
    float c2 = base[2 * 160 * 320];
    uint2 pk;
    pk.x = (uint)f2b(c0) | ((uint)f2b(c1) << 16);
    pk.y = (uint)f2b(c2);
    *(uint2*)(outp + ((size_t)((n * 164 + y + 2) * 328) + (x + 2)) * 4) = pk;
}

template <int HP, int WP, int H, int W, int CH>
__device__ __forceinline__ void halo_body(ushort* __restrict__ buf, int bid) {
    constexpr int TOPBOT = 2 * WP;
    constexpr int SIDE = WP - W;
    constexpr int NH = 2 * TOPBOT + H * SIDE;
    int idx = bid * 256 + threadIdx.x;
    if (idx >= 128 * NH) return;
    int n = idx / NH;
    int h = idx - n * NH;
    int y, x;
    if (h < TOPBOT) {
        y = h / WP;
        x = h % WP;
    } else if (h < 2 * TOPBOT) {
        int hh = h - TOPBOT;
        y = H + 2 + hh / WP;
        x = hh % WP;
    } else {
        int hh = h - 2 * TOPBOT;
        y = 2 + hh / SIDE;
        int xi = hh % SIDE;
        x = (xi < 2) ? xi : (W + xi);
    }
    ushort* p = buf + (((size_t)n * HP + y) * WP + x) * CH;
    if constexpr (CH == 4) {
        *(uint2*)p = make_uint2(0u, 0u);
    } else {
        uint4 z = make_uint4(0u, 0u, 0u, 0u);
#pragma unroll
        for (int i = 0; i < CH / 8; i++) *(uint4*)(p + i * 8) = z;
    }
}

__device__ __forceinline__ uint4 pack8(const ushort v[8]) {
    uint4 u;
    u.x = (uint)v[0] | ((uint)v[1] << 16);
    u.y = (uint)v[2] | ((uint)v[3] << 16);
    u.z = (uint)v[4] | ((uint)v[5] << 16);
    u.w = (uint)v[6] | ((uint)v[7] << 16);
    return u;
}

__device__ __forceinline__ void wswz1_body(const float* __restrict__ w, uint4* __restrict__ o,
                                           int i) {  // [0, 320)
    int lane = i & 63, s = i >> 6;
    int oc = lane & 15, q = lane >> 4;
    ushort v[8];
#pragma unroll
    for (int j = 0; j < 8; j++) {
        int k = q * 8 + j;
        int kx = k >> 2, c = k & 3;
        float f = (kx < 5 && c < 3) ? w[((oc * 3 + c) * 5 + s) * 5 + kx] : 0.f;
        v[j] = f2b(f);
    }
    o[i] = pack8(v);
}
__device__ __forceinline__ void wswz2_body(const float* __restrict__ w, uint4* __restrict__ o,
                                           int i) {  // [0, 1920)
    int lane = i & 63;
    int ct = (i >> 6) & 1;
    int s = i >> 7;
    int ky = s / 3, kxp = s % 3;
    int oc = ct * 16 + (lane & 15);
    int q = lane >> 4, h = q >> 1;
    int kx = 2 * kxp + h;
    ushort v[8];
#pragma unroll
    for (int j = 0; j < 8; j++) {
        int ch = (q & 1) * 8 + j;
        float f = (kx < 5) ? w[((oc * 16 + ch) * 5 + ky) * 5 + kx] : 0.f;
        v[j] = f2b(f);
    }
    o[i] = pack8(v);
}
__device__ __forceinline__ void wswz3_body(const float* __restrict__ w, uint4* __restrict__ o,
                                           int i) {  // [0, 1600)
    int lane = i & 63, s = i >> 6;
    int ky = s / 5, kx = s % 5;
    int oc = lane & 15, q = lane >> 4;
    ushort v[8];
#pragma unroll
    for (int j = 0; j < 8; j++) {
        int ch = q * 8 + j;
        float f = (oc < 8) ? w[((oc * 32 + ch) * 5 + ky) * 5 + kx] : 0.f;
        v[j] = f2b(f);
    }
    o[i] = pack8(v);
}

// ============ prep: cvt + halos + weight swizzles, ONE dispatch ============
__global__ __launch_bounds__(256) void prep_kernel(
    const float* __restrict__ in_seq, ushort* __restrict__ inp1, ushort* __restrict__ c1out,
    ushort* __restrict__ c2out, const float* __restrict__ c1w, const float* __restrict__ c2w,
    const float* __restrict__ c3w, uint4* __restrict__ wz1, uint4* __restrict__ wz2,
    uint4* __restrict__ wz3) {
    int bid = blockIdx.x;
    if (bid < 25600) {
        cvt_body(in_seq, inp1, bid * 256 + threadIdx.x);
    } else if (bid < 25600 + 2032) {
        int hb = bid - 25600;
        if (hb < 1296)
            halo_body<164, 328, 160, 320, 4>(inp1, hb);
        else if (hb < 1296 + 488)
            halo_body<84, 164, 80, 160, 16>(c1out, hb - 1296);
        else
            halo_body<44, 84, 40, 80, 32>(c2out, hb - 1784);
    } else {
        int i = (bid - 27632) * 256 + threadIdx.x;  // [0, 3840)
        if (i < 320)
            wswz1_body(c1w, wz1, i);
        else if (i < 2240)
            wswz2_body(c2w, wz2, i - 320);
        else
            wswz3_body(c3w, wz3, i - 2240);
    }
}

// ============ conv1: [128][164][328][4] -> [128][84][164][16], 5 ksteps (ky) ============
__global__ __launch_bounds__(256) void conv1_mfma(const ushort* __restrict__ inp,
                                                  const uint4* __restrict__ wswz,
                                                  const float* __restrict__ bias,
                                                  ushort* __restrict__ outp) {
    const int lane = threadIdx.x & 63;
    const int wid = threadIdx.x >> 6;
    const int col = lane & 15, q = lane >> 4;

    Frag A[5];
#pragma unroll
    for (int s = 0; s < 5; s++) A[s].u = wswz[s * 64 + lane];
    float b0 = bias[q * 4 + 0], b1 = bias[q * 4 + 1], b2 = bias[q * 4 + 2], b3 = bias[q * 4 + 3];

    int gw = blockIdx.x * 4 + wid;
#pragma unroll
    for (int t = 0; t < 4; t++) {
        int p0 = gw * 64 + t * 16;
        int n = p0 / 12800;
        int rem = p0 - n * 12800;
        int oy = rem / 160;
        int ox0 = rem - oy * 160;
        int ox = ox0 + col;
        uint e0 = ((uint)(n * 164 + oy * 2) * 328u + (uint)(ox * 2 + 2 * q)) * 4u;
        f32x4 acc = {0.f, 0.f, 0.f, 0.f};
#pragma unroll
        for (int s = 0; s < 5; s++) {
            Frag B;
            B.u = *(const uint4*)(inp + e0 + (uint)s * (328u * 4u));
            acc = __builtin_amdgcn_mfma_f32_16x16x32_bf16(A[s].s, B.s, acc, 0, 0, 0);
        }
        uint oe = ((uint)(n * 84 + oy + 2) * 164u + (uint)(ox + 2)) * 16u + q * 4u;
        uint2 pk;
        pk.x = (uint)f2b(fmaxf(acc[0] + b0, 0.f)) | ((uint)f2b(fmaxf(acc[1] + b1, 0.f)) << 16);
        pk.y = (uint)f2b(fmaxf(acc[2] + b2, 0.f)) | ((uint)f2b(fmaxf(acc[3] + b3, 0.f)) << 16);
        *(uint2*)(outp + oe) = pk;
    }
}

// ============ conv2: [128][84][164][16] -> [128][44][84][32], 15 ksteps ============
__global__ __launch_bounds__(256) void conv2_mfma(const ushort* __restrict__ inp,
                                                  const uint4* __restrict__ wswz,
                                                  const float* __restrict__ bias,
                                                  ushort* __restrict__ outp) {
    const int lane = threadIdx.x & 63;
    const int wid = threadIdx.x >> 6;
    const int col = lane & 15, q = lane >> 4;
    const int h = q >> 1, chh = q & 1;

    int gw = blockIdx.x * 4 + wid;
    uint eb[4];
#pragma unroll
    for (int t = 0; t < 4; t++) {
        int p0 = gw * 64 + t * 16;
        int n = p0 / 3200;
        int rem = p0 - n * 3200;
        int oy = rem / 80;
        int ox0 = rem - oy * 80;
        eb[t] = ((uint)(n * 84 + oy * 2) * 164u + (uint)((ox0 + col) * 2 + h)) * 16u + chh * 8u;
    }
    f32x4 acc[4][2];
#pragma unroll
    for (int t = 0; t < 4; t++) {
        acc[t][0] = {0.f, 0.f, 0.f, 0.f};
        acc[t][1] = {0.f, 0.f, 0.f, 0.f};
    }
#pragma unroll
    for (int s = 0; s < 15; s++) {
        const int ky = s / 3, kxp = s % 3;
        Frag A0, A1;
        A0.u = wswz[(s * 2 + 0) * 64 + lane];
        A1.u = wswz[(s * 2 + 1) * 64 + lane];
        const uint d = (uint)ky * (164u * 16u) + (uint)kxp * 32u;
#pragma unroll
        for (int t = 0; t < 4; t++) {
            Frag B;
            B.u = *(const uint4*)(inp + eb[t] + d);
            acc[t][0] = __builtin_amdgcn_mfma_f32_16x16x32_bf16(A0.s, B.s, acc[t][0], 0, 0, 0);
            acc[t][1] = __builtin_amdgcn_mfma_f32_16x16x32_bf16(A1.s, B.s, acc[t][1], 0, 0, 0);
        }
    }
    float ba[2][4];
#pragma unroll
    for (int c = 0; c < 2; c++)
#pragma unroll
        for (int r = 0; r < 4; r++) ba[c][r] = bias[c * 16 + q * 4 + r];
#pragma unroll
    for (int t = 0; t < 4; t++) {
        int p0 = gw * 64 + t * 16;
        int n = p0 / 3200;
        int rem = p0 - n * 3200;
        int oy = rem / 80;
        int ox0 = rem - oy * 80;
        int ox = ox0 + col;
        uint oe = ((uint)(n * 44 + oy + 2) * 84u + (uint)(ox + 2)) * 32u;
#pragma unroll
        for (int c = 0; c < 2; c++) {
            uint2 pk;
            pk.x = (uint)f2b(fmaxf(acc[t][c][0] + ba[c][0], 0.f)) |
                   ((uint)f2b(fmaxf(acc[t][c][1] + ba[c][1], 0.f)) << 16);
            pk.y = (uint)f2b(fmaxf(acc[t][c][2] + ba[c][2], 0.f)) |
                   ((uint)f2b(fmaxf(acc[t][c][3] + ba[c][3], 0.f)) << 16);
            *(uint2*)(outp + oe + (uint)c * 16u + (uint)q * 4u) = pk;
        }
    }
}

// ============ conv3: [128][44][84][32] -> [128][800][8] f32 (NHWC), 25 ksteps ============
__global__ __launch_bounds__(256) void conv3_mfma(const ushort* __restrict__ inp,
                                                  const uint4* __restrict__ wswz,
                                                  const float* __restrict__ bias,
                                                  float* __restrict__ outp) {
    const int lane = threadIdx.x & 63;
    const int wid = threadIdx.x >> 6;
    const int col = lane & 15, q = lane >> 4;

    int gw = blockIdx.x * 4 + wid;
    uint eb[4];
#pragma unroll
    for (int t = 0; t < 4; t++) {
        int p0 = gw * 64 + t * 16;
        int n = p0 / 800;
        int pix = p0 - n * 800 + col;  // per-lane coords (row-wrap safe, OW=40)
        int oy = pix / 40;
        int ox = pix - oy * 40;
        eb[t] = ((uint)(n * 44 + oy * 2) * 84u + (uint)(ox * 2)) * 32u + q * 8u;
    }
    f32x4 acc[4];
#pragma unroll
    for (int t = 0; t < 4; t++) acc[t] = {0.f, 0.f, 0.f, 0.f};
#pragma unroll
    for (int s = 0; s < 25; s++) {
        const int ky = s / 5, kx = s % 5;
        Frag A;
        A.u = wswz[s * 64 + lane];
        const uint d = ((uint)ky * 84u + (uint)kx) * 32u;
#pragma unroll
        for (int t = 0; t < 4; t++) {
            Frag B;
            B.u = *(const uint4*)(inp + eb[t] + d);
            acc[t] = __builtin_amdgcn_mfma_f32_16x16x32_bf16(A.s, B.s, acc[t], 0, 0, 0);
        }
    }
    if (q < 2) {
        float b0 = bias[q * 4 + 0], b1 = bias[q * 4 + 1];
        float b2 = bias[q * 4 + 2], b3 = bias[q * 4 + 3];
#pragma unroll
        for (int t = 0; t < 4; t++) {
            int p0 = gw * 64 + t * 16;
            int n = p0 / 800;
            int p = p0 - n * 800 + col;
            float4 v;
            v.x = fmaxf(acc[t][0] + b0, 0.f);
            v.y = fmaxf(acc[t][1] + b1, 0.f);
            v.z = fmaxf(acc[t][2] + b2, 0.f);
            v.w = fmaxf(acc[t][3] + b3, 0.f);
            *(float4*)(outp + ((size_t)n * 800 + p) * 8 + q * 4) = v;
        }
    }
}

// ============ head: 256 threads, 4-way p-split + LDS reduce ============
__global__ __launch_bounds__(256) void head_kernel(const float* __restrict__ x,
                                                   const float* __restrict__ hw,
                                                   const float* __restrict__ hb,
                                                   float* __restrict__ feats) {
    __shared__ float part[4][64];
    int n = blockIdx.x;
    int tid = threadIdx.x;
    int lane = tid & 63;
    int c = tid >> 6;  // p-chunk 0..3
    int f = lane >> 3;
    int k = lane & 7;
    const float* xb = x + (size_t)n * 800 * 8 + f;
    const float* wb = hw + ((size_t)f * 800) * FPF + k;
    float acc = 0.0f;
    for (int p = c * 200; p < c * 200 + 200; p++)
        acc = fmaf(xb[(size_t)p * 8], wb[(size_t)p * FPF], acc);
    part[c][lane] = acc;
    __syncthreads();
    if (c == 0)
        feats[n * 64 + lane] = part[0][lane] + part[1][lane] + part[2][lane] + part[3][lane] +
                               hb[lane];
}

// ============ stats: 1 block x 1024 threads (16 waves of latency hiding) ============
__global__ __launch_bounds__(1024) void stats_kernel(const float* __restrict__ feats,
                                                     float* __restrict__ invstd) {
    __shared__ float2 red[1024];
    int tid = threadIdx.x;
    float s = 0.0f, q = 0.0f;
    for (int i = tid; i < 8192; i += 1024) {
        float x = feats[i];
        s += x;
        q += x * x;
    }
    red[tid] = make_float2(s, q);
    __syncthreads();
    for (int off = 512; off > 0; off >>= 1) {
        if (tid < off) {
            float2 o = red[tid + off];
            float2 m = red[tid];
            red[tid] = make_float2(m.x + o.x, m.y + o.y);
        }
        __syncthreads();
    }
    if (tid == 0) {
        float mean = red[0].x / 8192.0f;
        float var = fmaxf((red[0].y - 8192.0f * mean * mean) / 8191.0f, 0.0f);
        invstd[0] = 1.0f / (sqrtf(var) + 1e-5f);
    }
}

// ============ sensory (+inlined semb): 128 blocks x 64 threads ============
__global__ __launch_bounds__(64) void sensory_kernel(
    const float* __restrict__ feats, const float* __restrict__ speed,
    const float* __restrict__ sew1, const float* __restrict__ seb1,
    const float* __restrict__ sew2, const float* __restrict__ seb2,
    const float* __restrict__ invstd, const float* __restrict__ inw,
    const float* __restrict__ inb, const float* __restrict__ ssig,
    const float* __restrict__ smu, const float* __restrict__ sw,
    const float* __restrict__ serev, float* __restrict__ wns, float* __restrict__ wds) {
    int bid = blockIdx.x;  // t*4 + b
    int t = bid >> 2;
    int b = bid & 3;
    int u = threadIdx.x;  // 0..63
    int n = b * TT + t;
    float inv = invstd[0];

    float sp = speed[n];
    float h[16];
#pragma unroll
    for (int j = 0; j < 16; j++) h[j] = fmaxf(fmaf(sp, sew1[j], seb1[j]), 0.0f);
    float embv[SDIM];
#pragma unroll
    for (int k = 0; k < SDIM; k++) {
        float a = seb2[k];
#pragma unroll
        for (int j = 0; j < 16; j++) a = fmaf(h[j], sew2[j * SDIM + k], a);
        embv[k] = tanhf(a);
    }

    float num = 0.0f, den = 0.0f;
#pragma unroll 4
    for (int ss = 0; ss < 64; ss++) {
        float xsv = feats[n * 64 + ss] * inv;
        float inp = fmaf(xsv, inw[ss], inb[ss]);
        int idx = ss * UU + u;
        float x = (inp - smu[idx]) * ssig[idx];
        float act = sw[idx] * fast_sigmoid(x);
        num = fmaf(act, serev[idx], num);
        den += act;
    }
#pragma unroll
    for (int ss = 64; ss < SS; ss++) {
        float inp = fmaf(embv[ss - 64], inw[ss], inb[ss]);
        int idx = ss * UU + u;
        float x = (inp - smu[idx]) * ssig[idx];
        float act = sw[idx] * fast_sigmoid(x);
        num = fmaf(act, serev[idx], num);
        den += act;
    }
    wns[bid * UU + u] = num;
    wds[bid * UU + u] = den;
}

// ============ LTC scan (R7): 8 waves, lgkm-only barrier, SGPR lane index ============
__global__ __launch_bounds__(512, 1) void scan_kernel(
    const float* __restrict__ wns, const float* __restrict__ wds,
    const float* __restrict__ gleak, const float* __restrict__ vleak,
    const float* __restrict__ cm, const float* __restrict__ sigma,
    const float* __restrict__ mu, const float* __restrict__ wsyn,
    const float* __restrict__ erev, const float* __restrict__ outw,
    const float* __restrict__ outb, float* __restrict__ dout) {
    int b = blockIdx.x;
    int tid = threadIdx.x;
    int u = tid & 63;
    int pc_s = __builtin_amdgcn_readfirstlane(tid >> 6);  // 0..7

    __shared__ float2 pbuf[2][8][64];

    float sA[8], sB[8], wer[8], w_[8];
#pragma unroll
    for (int i = 0; i < 8; i++) {
        int idx = (pc_s * 8 + i) * UU + u;
        float sg = sigma[idx];
        sA[i] = -1.44269504f * sg;
        sB[i] = -sA[i] * mu[idx];
        w_[i] = wsyn[idx];
        wer[i] = w_[i] * erev[idx];
    }
#pragma unroll
    for (int i = 0; i < 8; i++) {
        asm volatile("" : "+v"(sA[i]), "+v"(sB[i]), "+v"(wer[i]), "+v"(w_[i]));
    }
    float cmt = cm[u] * (float)UNFOLDS;
    float gl = gleak[u];
    float glvl = gl * vleak[u];
    float ow = outw[0], ob = outb[0];
    float v = 0.0f;
    int par = 0;

    float num_s = wns[(0 * BB + b) * UU + u];
    float den_s = wds[(0 * BB + b) * UU + u];
    for (int t = 0; t < TT; t++) {
        float nns = 0.f, nds = 0.f;
        if (t + 1 < TT) {
            nns = wns[((t + 1) * BB + b) * UU + u];
            nds = wds[((t + 1) * BB + b) * UU + u];
        }
#pragma unroll
        for (int k = 0; k < UNFOLDS; k++) {
            float num = 0.0f, den = 0.0f;
#pragma unroll
            for (int i = 0; i < 8; i++) {
                float vi = bcast_lane(v, pc_s * 8 + i);
                float e = exp2f(fmaf(vi, sA[i], sB[i]));
                float r = __builtin_amdgcn_rcpf(1.0f + e);
                num = fmaf(wer[i], r, num);
                den = fmaf(w_[i], r, den);
            }
            pbuf[par][pc_s][u] = make_float2(num, den);
            __builtin_amdgcn_sched_barrier(0);
            asm volatile("s_waitcnt lgkmcnt(0)" ::: "memory");
            __builtin_amdgcn_s_barrier();
            asm volatile("" ::: "memory");
            __builtin_amdgcn_sched_barrier(0);
            float nn = num_s, dd = den_s;
#pragma unroll
            for (int j = 0; j < 8; j++) {
                float2 p = pbuf[par][j][u];
                nn += p.x;
                dd += p.y;
            }
            float denom = cmt + gl + dd + 1e-8f;
            v = (fmaf(cmt, v, glvl) + nn) * __builtin_amdgcn_rcpf(denom);
            par ^= 1;
        }
        if (pc_s == 0) {
            dout[384 + (b * TT + t) * UU + u] = v;
            if (u == 0) dout[b * TT + t] = fmaf(v, ow, ob);
            if (t == TT - 1) dout[128 + b * UU + u] = v;
        }
        num_s = nns;
        den_s = nds;
    }
}

extern "C" void kernel_launch(void* const* d_in, const int* in_sizes, int n_in,
                              void* d_out, int out_size, void* d_ws, size_t ws_size,
                              hipStream_t stream) {
    const float* in_seq = (const float*)d_in[0];
    const float* speed = (const float*)d_in[1];
    const float* c1w = (const float*)d_in[2];
    const float* c1b = (const float*)d_in[3];
    const float* c2w = (const float*)d_in[4];
    const float* c2b = (const float*)d_in[5];
    const float* c3w = (const float*)d_in[6];
    const float* c3b = (const float*)d_in[7];
    const float* hw = (const float*)d_in[8];
    const float* hb = (const float*)d_in[9];
    const float* sew1 = (const float*)d_in[10];
    const float* seb1 = (const float*)d_in[11];
    const float* sew2 = (const float*)d_in[12];
    const float* seb2 = (const float*)d_in[13];
    const float* inw = (const float*)d_in[14];
    const float* inb = (const float*)d_in[15];
    const float* gleak = (const float*)d_in[16];
    const float* vleak = (const float*)d_in[17];
    const float* cm = (const float*)d_in[18];
    const float* sigma = (const float*)d_in[19];
    const float* mu = (const float*)d_in[20];
    const float* wsyn = (const float*)d_in[21];
    const float* erev = (const float*)d_in[22];
    const float* ssig = (const float*)d_in[23];
    const float* smu = (const float*)d_in[24];
    const float* sw = (const float*)d_in[25];
    const float* serev = (const float*)d_in[26];
    const float* outw = (const float*)d_in[27];
    const float* outb = (const float*)d_in[28];

    char* ws = (char*)d_ws;
    float* out = (float*)d_out;

    size_t off = 0;
    auto alloc = [&](size_t bytes) {
        size_t o = off;
        off += (bytes + 255) & ~(size_t)255;
        return o;
    };
    ushort* inp1 = (ushort*)(ws + alloc((size_t)128 * 164 * 328 * 4 * 2));
    ushort* c1out = (ushort*)(ws + alloc((size_t)128 * 84 * 164 * 16 * 2));
    ushort* c2out = (ushort*)(ws + alloc((size_t)128 * 44 * 84 * 32 * 2));
    float* c3out = (float*)(ws + alloc((size_t)128 * 800 * 8 * 4));
    float* feats = (float*)(ws + alloc(8192 * 4));
    float* invstd = (float*)(ws + alloc(64));
    float* wns = (float*)(ws + alloc(8192 * 4));
    float* wds = (float*)(ws + alloc(8192 * 4));
    uint4* wz1 = (uint4*)(ws + alloc(5 * 64 * 16));
    uint4* wz2 = (uint4*)(ws + alloc(30 * 64 * 16));
    uint4* wz3 = (uint4*)(ws + alloc(25 * 64 * 16));

    // 1) prep: cvt + halo fills + weight swizzles
    prep_kernel<<<27647, 256, 0, stream>>>(in_seq, inp1, c1out, c2out, c1w, c2w, c3w, wz1,
                                           wz2, wz3);

    // 2-4) MFMA convs
    conv1_mfma<<<6400, 256, 0, stream>>>(inp1, wz1, c1b, c1out);
    conv2_mfma<<<1600, 256, 0, stream>>>(c1out, wz2, c2b, c2out);
    conv3_mfma<<<400, 256, 0, stream>>>(c2out, wz3, c3b, c3out);

    // 5) head
    head_kernel<<<128, 256, 0, stream>>>(c3out, hw, hb, feats);

    // 6) stats (1 block, 16 waves)
    stats_kernel<<<1, 1024, 0, stream>>>(feats, invstd);

    // 7) sensory (+semb inline)
    sensory_kernel<<<128, 64, 0, stream>>>(feats, speed, sew1, seb1, sew2, seb2, invstd, inw,
                                           inb, ssig, smu, sw, serev, wns, wds);

    // 8) serial LTC scan
    scan_kernel<<<BB, 512, 0, stream>>>(wns, wds, gleak, vleak, cm, sigma, mu, wsyn, erev,
                                        outw, outb, out);
}